// Round 1
// baseline (2312.431 us; speedup 1.0000x reference)
//
#include <hip/hip_runtime.h>

#define NN 100000
#define NE 1600000
#define NG 256

// ---------------- degree ----------------
__global__ void deg_kernel(const int* __restrict__ dst, float* __restrict__ cnt, int E) {
    int e = blockIdx.x * blockDim.x + threadIdx.x;
    if (e < E) unsafeAtomicAdd(&cnt[dst[e]], 1.0f);
}

__global__ void deginv_kernel(const float* __restrict__ cnt, float* __restrict__ deg_inv, int N) {
    int n = blockIdx.x * blockDim.x + threadIdx.x;
    if (n < N) deg_inv[n] = rsqrtf(1.0f + cnt[n]);
}

// ---------------- GEMM1: [N,128] @ [128,32] ----------------
__global__ __launch_bounds__(256) void gemm_x_w1(const float* __restrict__ x,
                                                 const float* __restrict__ W,
                                                 float* __restrict__ h, int N) {
    __shared__ float wsh[128 * 32];
    __shared__ float xs[8][128];
    int tid = threadIdx.x;
    for (int i = tid; i < 128 * 32 / 4; i += 256)
        ((float4*)wsh)[i] = ((const float4*)W)[i];
    int row0 = blockIdx.x * 8;
    {
        int r = tid / 32, c4 = tid % 32;  // 128 floats = 32 float4 per row
        int row = row0 + r;
        float4 v = make_float4(0.f, 0.f, 0.f, 0.f);
        if (row < N) v = ((const float4*)x)[row * 32 + c4];
        ((float4*)xs[r])[c4] = v;
    }
    __syncthreads();
    int r = tid / 32, c = tid % 32;
    int row = row0 + r;
    float acc = 0.f;
#pragma unroll 8
    for (int k = 0; k < 128; ++k)
        acc += xs[r][k] * wsh[k * 32 + c];
    if (row < N) h[row * 32 + c] = acc;
}

// ---------------- GEMM2: [N,32] @ [32,64] ----------------
__global__ __launch_bounds__(256) void gemm_h_w2(const float* __restrict__ a,
                                                 const float* __restrict__ W,
                                                 float* __restrict__ h, int N) {
    __shared__ float wsh[32 * 64];
    __shared__ float xs[4][32];
    int tid = threadIdx.x;
    for (int i = tid; i < 32 * 64 / 4; i += 256)
        ((float4*)wsh)[i] = ((const float4*)W)[i];
    int row0 = blockIdx.x * 4;
    if (tid < 128) {
        int r = tid / 32, c = tid % 32;
        int row = row0 + r;
        xs[r][c] = (row < N) ? a[row * 32 + c] : 0.f;
    }
    __syncthreads();
    int r = tid / 64, c = tid % 64;
    int row = row0 + r;
    float acc = 0.f;
#pragma unroll
    for (int k = 0; k < 32; ++k)
        acc += xs[r][k] * wsh[k * 64 + c];
    if (row < N) h[row * 64 + c] = acc;
}

// ---------------- self-loop init: out = deg_inv^2 * h + b ----------------
template <int F>
__global__ void self_init(const float* __restrict__ h, const float* __restrict__ deg_inv,
                          const float* __restrict__ b, float* __restrict__ out, int N) {
    int i = blockIdx.x * blockDim.x + threadIdx.x;
    if (i >= N * F) return;
    int n = i / F, f = i % F;
    float di = deg_inv[n];
    out[i] = di * di * h[i] + b[f];
}

// ---------------- edge scatter: out[dst] += norm * h[src] ----------------
template <int F>
__global__ void edge_scatter(const int* __restrict__ src, const int* __restrict__ dst,
                             const float* __restrict__ deg_inv, const float* __restrict__ h,
                             float* __restrict__ out, int E) {
    const int Gp = F / 4;  // float4 groups per edge
    int gid = blockIdx.x * blockDim.x + threadIdx.x;
    if (gid >= E * Gp) return;
    int e = gid / Gp;
    int g = gid % Gp;
    int s = src[e], d = dst[e];
    float norm = deg_inv[s] * deg_inv[d];
    float4 v = ((const float4*)(h + (size_t)s * F))[g];
    float* o = out + (size_t)d * F + g * 4;
    unsafeAtomicAdd(o + 0, v.x * norm);
    unsafeAtomicAdd(o + 1, v.y * norm);
    unsafeAtomicAdd(o + 2, v.z * norm);
    unsafeAtomicAdd(o + 3, v.w * norm);
}

// ---------------- pooling: segment sum + count, run-length pre-reduced ----------------
__global__ void pool_kernel(const float* __restrict__ h, const int* __restrict__ batch,
                            float* __restrict__ gsum, float* __restrict__ gcnt, int N) {
    int t = blockIdx.x * blockDim.x + threadIdx.x;
    int chunk = t / 64;
    int f = t % 64;
    int n0 = chunk * 16;
    if (n0 >= N) return;
    int n1 = min(n0 + 16, N);
    int cur = batch[n0];
    float acc = 0.f, ccnt = 0.f;
    for (int n = n0; n < n1; ++n) {
        int b = batch[n];
        if (b != cur) {
            unsafeAtomicAdd(&gsum[cur * 64 + f], acc);
            if (f == 0) unsafeAtomicAdd(&gcnt[cur], ccnt);
            acc = 0.f; ccnt = 0.f; cur = b;
        }
        acc += h[(size_t)n * 64 + f];
        ccnt += 1.f;
    }
    unsafeAtomicAdd(&gsum[cur * 64 + f], acc);
    if (f == 0) unsafeAtomicAdd(&gcnt[cur], ccnt);
}

// ---------------- head: fc1+relu -> batchnorm -> fc2 -> softplus ----------------
__global__ __launch_bounds__(256) void head_kernel(const float* __restrict__ gsum,
                                                   const float* __restrict__ gcnt,
                                                   const float* __restrict__ fcW1,
                                                   const float* __restrict__ fcb1,
                                                   const float* __restrict__ gamma,
                                                   const float* __restrict__ beta,
                                                   const float* __restrict__ fcW2,
                                                   const float* __restrict__ fcb2,
                                                   float* __restrict__ out) {
    __shared__ float zs[NG][33];
    __shared__ float mu[32], rstd[32];
    int g = threadIdx.x;
    float pooled[64];
    float c = fmaxf(gcnt[g], 1.0f);
    float inv = 1.0f / c;
#pragma unroll
    for (int k = 0; k < 64; ++k) pooled[k] = gsum[g * 64 + k] * inv;
    for (int ch = 0; ch < 32; ++ch) {
        float acc = fcb1[ch];
#pragma unroll
        for (int k = 0; k < 64; ++k) acc += pooled[k] * fcW1[k * 32 + ch];
        zs[g][ch] = fmaxf(acc, 0.f);
    }
    __syncthreads();
    if (g < 32) {
        float s = 0.f;
        for (int i = 0; i < NG; ++i) s += zs[i][g];
        float m = s / NG;
        float v = 0.f;
        for (int i = 0; i < NG; ++i) { float d = zs[i][g] - m; v += d * d; }
        v /= NG;
        mu[g] = m;
        rstd[g] = rsqrtf(v + 1e-5f);
    }
    __syncthreads();
    float acc = fcb2[0];
    for (int ch = 0; ch < 32; ++ch) {
        float zn = (zs[g][ch] - mu[ch]) * rstd[ch] * gamma[ch] + beta[ch];
        acc += zn * fcW2[ch];
    }
    out[g] = fmaxf(acc, 0.f) + log1pf(expf(-fabsf(acc)));
}

extern "C" void kernel_launch(void* const* d_in, const int* in_sizes, int n_in,
                              void* d_out, int out_size, void* d_ws, size_t ws_size,
                              hipStream_t stream) {
    const float* x     = (const float*)d_in[0];
    const int*   ei    = (const int*)d_in[1];
    const int*   batch = (const int*)d_in[2];
    const float* W1    = (const float*)d_in[3];
    const float* b1    = (const float*)d_in[4];
    const float* W2    = (const float*)d_in[5];
    const float* b2    = (const float*)d_in[6];
    const float* fcW1  = (const float*)d_in[7];
    const float* fcb1  = (const float*)d_in[8];
    const float* gamma = (const float*)d_in[9];
    const float* beta  = (const float*)d_in[10];
    const float* fcW2  = (const float*)d_in[11];
    const float* fcb2  = (const float*)d_in[12];
    float* out = (float*)d_out;

    float* ws      = (float*)d_ws;
    float* cnt     = ws;                    // NN
    float* deg_inv = cnt + NN;              // NN
    float* h1      = deg_inv + NN;          // NN*32
    float* out1    = h1 + (size_t)NN * 32;  // NN*32
    float* h2      = out1 + (size_t)NN * 32;// NN*64
    float* out2    = h2 + (size_t)NN * 64;  // NN*64
    float* gsum    = out2 + (size_t)NN * 64;// NG*64
    float* gcnt    = gsum + NG * 64;        // NG

    const int* srcv = ei;
    const int* dstv = ei + NE;

    hipMemsetAsync(cnt, 0, NN * sizeof(float), stream);
    hipMemsetAsync(gsum, 0, (NG * 64 + NG) * sizeof(float), stream);

    deg_kernel<<<(NE + 255) / 256, 256, 0, stream>>>(dstv, cnt, NE);
    deginv_kernel<<<(NN + 255) / 256, 256, 0, stream>>>(cnt, deg_inv, NN);

    gemm_x_w1<<<(NN + 7) / 8, 256, 0, stream>>>(x, W1, h1, NN);
    self_init<32><<<((size_t)NN * 32 + 255) / 256, 256, 0, stream>>>(h1, deg_inv, b1, out1, NN);
    edge_scatter<32><<<((size_t)NE * 8 + 255) / 256, 256, 0, stream>>>(srcv, dstv, deg_inv, h1, out1, NE);

    gemm_h_w2<<<(NN + 3) / 4, 256, 0, stream>>>(out1, W2, h2, NN);
    self_init<64><<<((size_t)NN * 64 + 255) / 256, 256, 0, stream>>>(h2, deg_inv, b2, out2, NN);
    edge_scatter<64><<<((size_t)NE * 16 + 255) / 256, 256, 0, stream>>>(srcv, dstv, deg_inv, h2, out2, NE);

    pool_kernel<<<(((NN + 15) / 16) * 64 + 255) / 256, 256, 0, stream>>>(out2, batch, gsum, gcnt, NN);
    head_kernel<<<1, 256, 0, stream>>>(gsum, gcnt, fcW1, fcb1, gamma, beta, fcW2, fcb2, out);
}

// Round 2
// 568.223 us; speedup vs baseline: 4.0696x; 4.0696x over previous
//
#include <hip/hip_runtime.h>

#define NN 100000
#define NE 1600000
#define NG 256
#define SCAN_CHUNK 1024
#define NB_SCAN ((NN + SCAN_CHUNK - 1) / SCAN_CHUNK)  // 98

// ---------------- degree histogram (int) ----------------
__global__ void hist_kernel(const int* __restrict__ dst, int* __restrict__ cnt, int E) {
    int e = blockIdx.x * blockDim.x + threadIdx.x;
    if (e < E) atomicAdd(&cnt[dst[e]], 1);
}

__global__ void deginv_kernel(const int* __restrict__ cnt, float* __restrict__ deg_inv, int N) {
    int n = blockIdx.x * blockDim.x + threadIdx.x;
    if (n < N) deg_inv[n] = rsqrtf(1.0f + (float)cnt[n]);
}

// ---------------- exclusive scan (3 kernels) ----------------
__global__ __launch_bounds__(256) void scan1_kernel(const int* __restrict__ cnt,
                                                    int* __restrict__ part,
                                                    int* __restrict__ bsum) {
    __shared__ int ts[256];
    int tid = threadIdx.x;
    int base = blockIdx.x * SCAN_CHUNK + tid * 4;
    int v[4];
    int s = 0;
#pragma unroll
    for (int i = 0; i < 4; ++i) {
        v[i] = (base + i < NN) ? cnt[base + i] : 0;
        s += v[i];
    }
    ts[tid] = s;
    __syncthreads();
    for (int off = 1; off < 256; off <<= 1) {
        int t = (tid >= off) ? ts[tid - off] : 0;
        __syncthreads();
        ts[tid] += t;
        __syncthreads();
    }
    int run = ts[tid] - s;  // exclusive prefix for this thread
#pragma unroll
    for (int i = 0; i < 4; ++i) {
        if (base + i < NN) part[base + i] = run;
        run += v[i];
    }
    if (tid == 255) bsum[blockIdx.x] = ts[255];
}

__global__ __launch_bounds__(128) void scan2_kernel(const int* __restrict__ bsum,
                                                    int* __restrict__ bsumex) {
    __shared__ int ts[128];
    int tid = threadIdx.x;
    int v = (tid < NB_SCAN) ? bsum[tid] : 0;
    ts[tid] = v;
    __syncthreads();
    for (int off = 1; off < 128; off <<= 1) {
        int t = (tid >= off) ? ts[tid - off] : 0;
        __syncthreads();
        ts[tid] += t;
        __syncthreads();
    }
    bsumex[tid] = ts[tid] - v;
}

__global__ __launch_bounds__(256) void scan3_kernel(const int* __restrict__ part,
                                                    const int* __restrict__ bsumex,
                                                    int* __restrict__ row_ptr,
                                                    int* __restrict__ cursor) {
    int tid = threadIdx.x;
    int base = blockIdx.x * SCAN_CHUNK + tid * 4;
    int add = bsumex[blockIdx.x];
#pragma unroll
    for (int i = 0; i < 4; ++i) {
        int idx = base + i;
        if (idx < NN) {
            int v = part[idx] + add;
            row_ptr[idx] = v;
            cursor[idx] = v;
        }
    }
    if (blockIdx.x == 0 && tid == 0) row_ptr[NN] = NE;
}

// ---------------- CSR fill ----------------
__global__ void fill_kernel(const int* __restrict__ src, const int* __restrict__ dst,
                            int* __restrict__ cursor, int* __restrict__ col, int E) {
    int e = blockIdx.x * blockDim.x + threadIdx.x;
    if (e >= E) return;
    int d = dst[e];
    int pos = atomicAdd(&cursor[d], 1);
    col[pos] = src[e];
}

// ---------------- GEMM1: [N,128] @ [128,32], epilogue scale by deg_inv ----------------
__global__ __launch_bounds__(256) void gemm_x_w1(const float* __restrict__ x,
                                                 const float* __restrict__ W,
                                                 const float* __restrict__ deg_inv,
                                                 float* __restrict__ h, int N) {
    __shared__ float wsh[128 * 32];
    __shared__ float xs[8][128];
    int tid = threadIdx.x;
    for (int i = tid; i < 128 * 32 / 4; i += 256)
        ((float4*)wsh)[i] = ((const float4*)W)[i];
    int row0 = blockIdx.x * 8;
    {
        int r = tid / 32, c4 = tid % 32;
        int row = row0 + r;
        float4 v = make_float4(0.f, 0.f, 0.f, 0.f);
        if (row < N) v = ((const float4*)x)[row * 32 + c4];
        ((float4*)xs[r])[c4] = v;
    }
    __syncthreads();
    int r = tid / 32, c = tid % 32;
    int row = row0 + r;
    float acc = 0.f;
#pragma unroll 8
    for (int k = 0; k < 128; ++k)
        acc += xs[r][k] * wsh[k * 32 + c];
    if (row < N) h[row * 32 + c] = acc * deg_inv[row];
}

// ---------------- GEMM2: [N,32] @ [32,64], epilogue scale by deg_inv ----------------
__global__ __launch_bounds__(256) void gemm_h_w2(const float* __restrict__ a,
                                                 const float* __restrict__ W,
                                                 const float* __restrict__ deg_inv,
                                                 float* __restrict__ h, int N) {
    __shared__ float wsh[32 * 64];
    __shared__ float xs[4][32];
    int tid = threadIdx.x;
    for (int i = tid; i < 32 * 64 / 4; i += 256)
        ((float4*)wsh)[i] = ((const float4*)W)[i];
    int row0 = blockIdx.x * 4;
    if (tid < 128) {
        int r = tid / 32, c = tid % 32;
        int row = row0 + r;
        xs[r][c] = (row < N) ? a[row * 32 + c] : 0.f;
    }
    __syncthreads();
    int r = tid / 64, c = tid % 64;
    int row = row0 + r;
    float acc = 0.f;
#pragma unroll
    for (int k = 0; k < 32; ++k)
        acc += xs[r][k] * wsh[k * 64 + c];
    if (row < N) h[row * 64 + c] = acc * deg_inv[row];
}

// ---------------- gather conv, F=32: one node per 32 lanes ----------------
// out[d] = deg_inv[d] * (h_s[d] + sum_{e in CSR[d]} h_s[col_e]) + b
__global__ __launch_bounds__(256) void conv32_kernel(const int* __restrict__ row_ptr,
                                                     const int* __restrict__ col,
                                                     const float* __restrict__ h_s,
                                                     const float* __restrict__ deg_inv,
                                                     const float* __restrict__ b,
                                                     float* __restrict__ out) {
    int gid = blockIdx.x * blockDim.x + threadIdx.x;
    int node = gid >> 5;
    int lane = gid & 31;
    if (node >= NN) return;
    int beg = row_ptr[node], end = row_ptr[node + 1];
    float acc = h_s[(size_t)node * 32 + lane];  // self loop
    for (int j0 = beg; j0 < end; j0 += 32) {
        int idx = j0 + lane;
        int myc = (idx < end) ? col[idx] : 0;
        int m = end - j0;
        if (m > 32) m = 32;
        for (int t = 0; t < m; ++t) {
            int c = __shfl(myc, t, 32);
            acc += h_s[(size_t)c * 32 + lane];
        }
    }
    out[(size_t)node * 32 + lane] = deg_inv[node] * acc + b[lane];
}

// ---------------- gather conv, F=64: one node per wave ----------------
__global__ __launch_bounds__(256) void conv64_kernel(const int* __restrict__ row_ptr,
                                                     const int* __restrict__ col,
                                                     const float* __restrict__ h_s,
                                                     const float* __restrict__ deg_inv,
                                                     const float* __restrict__ b,
                                                     float* __restrict__ out) {
    int gid = blockIdx.x * blockDim.x + threadIdx.x;
    int node = gid >> 6;
    int lane = gid & 63;
    if (node >= NN) return;
    int beg = row_ptr[node], end = row_ptr[node + 1];
    float acc = h_s[(size_t)node * 64 + lane];  // self loop
    for (int j0 = beg; j0 < end; j0 += 64) {
        int idx = j0 + lane;
        int myc = (idx < end) ? col[idx] : 0;
        int m = end - j0;
        if (m > 64) m = 64;
        for (int t = 0; t < m; ++t) {
            int c = __shfl(myc, t, 64);
            acc += h_s[(size_t)c * 64 + lane];
        }
    }
    out[(size_t)node * 64 + lane] = deg_inv[node] * acc + b[lane];
}

// ---------------- pooling: segment sum + count, run-length pre-reduced ----------------
__global__ void pool_kernel(const float* __restrict__ h, const int* __restrict__ batch,
                            float* __restrict__ gsum, float* __restrict__ gcnt, int N) {
    int t = blockIdx.x * blockDim.x + threadIdx.x;
    int chunk = t / 64;
    int f = t % 64;
    int n0 = chunk * 16;
    if (n0 >= N) return;
    int n1 = min(n0 + 16, N);
    int cur = batch[n0];
    float acc = 0.f, ccnt = 0.f;
    for (int n = n0; n < n1; ++n) {
        int b = batch[n];
        if (b != cur) {
            unsafeAtomicAdd(&gsum[cur * 64 + f], acc);
            if (f == 0) unsafeAtomicAdd(&gcnt[cur], ccnt);
            acc = 0.f; ccnt = 0.f; cur = b;
        }
        acc += h[(size_t)n * 64 + f];
        ccnt += 1.f;
    }
    unsafeAtomicAdd(&gsum[cur * 64 + f], acc);
    if (f == 0) unsafeAtomicAdd(&gcnt[cur], ccnt);
}

// ---------------- head: fc1+relu -> batchnorm -> fc2 -> softplus ----------------
__global__ __launch_bounds__(256) void head_kernel(const float* __restrict__ gsum,
                                                   const float* __restrict__ gcnt,
                                                   const float* __restrict__ fcW1,
                                                   const float* __restrict__ fcb1,
                                                   const float* __restrict__ gamma,
                                                   const float* __restrict__ beta,
                                                   const float* __restrict__ fcW2,
                                                   const float* __restrict__ fcb2,
                                                   float* __restrict__ out) {
    __shared__ float zs[NG][33];
    __shared__ float mu[32], rstd[32];
    int g = threadIdx.x;
    float pooled[64];
    float c = fmaxf(gcnt[g], 1.0f);
    float inv = 1.0f / c;
#pragma unroll
    for (int k = 0; k < 64; ++k) pooled[k] = gsum[g * 64 + k] * inv;
    for (int ch = 0; ch < 32; ++ch) {
        float acc = fcb1[ch];
#pragma unroll
        for (int k = 0; k < 64; ++k) acc += pooled[k] * fcW1[k * 32 + ch];
        zs[g][ch] = fmaxf(acc, 0.f);
    }
    __syncthreads();
    if (g < 32) {
        float s = 0.f;
        for (int i = 0; i < NG; ++i) s += zs[i][g];
        float m = s / NG;
        float v = 0.f;
        for (int i = 0; i < NG; ++i) { float d = zs[i][g] - m; v += d * d; }
        v /= NG;
        mu[g] = m;
        rstd[g] = rsqrtf(v + 1e-5f);
    }
    __syncthreads();
    float acc = fcb2[0];
    for (int ch = 0; ch < 32; ++ch) {
        float zn = (zs[g][ch] - mu[ch]) * rstd[ch] * gamma[ch] + beta[ch];
        acc += zn * fcW2[ch];
    }
    out[g] = fmaxf(acc, 0.f) + log1pf(expf(-fabsf(acc)));
}

extern "C" void kernel_launch(void* const* d_in, const int* in_sizes, int n_in,
                              void* d_out, int out_size, void* d_ws, size_t ws_size,
                              hipStream_t stream) {
    const float* x     = (const float*)d_in[0];
    const int*   ei    = (const int*)d_in[1];
    const int*   batch = (const int*)d_in[2];
    const float* W1    = (const float*)d_in[3];
    const float* b1    = (const float*)d_in[4];
    const float* W2    = (const float*)d_in[5];
    const float* b2    = (const float*)d_in[6];
    const float* fcW1  = (const float*)d_in[7];
    const float* fcb1  = (const float*)d_in[8];
    const float* gamma = (const float*)d_in[9];
    const float* beta  = (const float*)d_in[10];
    const float* fcW2  = (const float*)d_in[11];
    const float* fcb2  = (const float*)d_in[12];
    float* out = (float*)d_out;

    // workspace layout (all chunks multiple of 8 elements => 16B aligned)
    char* p = (char*)d_ws;
    int*   cnt     = (int*)p;        p += (size_t)NN * 4;        // NN ints
    float* deg_inv = (float*)p;      p += (size_t)NN * 4;
    int*   row_ptr = (int*)p;        p += (size_t)(NN + 8) * 4;
    int*   cursor  = (int*)p;        p += (size_t)NN * 4;
    int*   part    = (int*)p;        p += (size_t)NN * 4;
    int*   bsum    = (int*)p;        p += 128 * 4;
    int*   bsumex  = (int*)p;        p += 128 * 4;
    int*   col     = (int*)p;        p += (size_t)NE * 4;
    float* h1s     = (float*)p;      p += (size_t)NN * 32 * 4;
    float* out1    = (float*)p;      p += (size_t)NN * 32 * 4;
    float* h2s     = (float*)p;      p += (size_t)NN * 64 * 4;
    float* out2    = (float*)p;      p += (size_t)NN * 64 * 4;
    float* gsum    = (float*)p;      p += (size_t)NG * 64 * 4;
    float* gcnt    = (float*)p;      p += (size_t)NG * 4;

    const int* srcv = ei;
    const int* dstv = ei + NE;

    hipMemsetAsync(cnt, 0, NN * sizeof(int), stream);
    hipMemsetAsync(gsum, 0, (NG * 64 + NG) * sizeof(float), stream);

    // CSR build
    hist_kernel<<<(NE + 255) / 256, 256, 0, stream>>>(dstv, cnt, NE);
    deginv_kernel<<<(NN + 255) / 256, 256, 0, stream>>>(cnt, deg_inv, NN);
    scan1_kernel<<<NB_SCAN, 256, 0, stream>>>(cnt, part, bsum);
    scan2_kernel<<<1, 128, 0, stream>>>(bsum, bsumex);
    scan3_kernel<<<NB_SCAN, 256, 0, stream>>>(part, bsumex, row_ptr, cursor);
    fill_kernel<<<(NE + 255) / 256, 256, 0, stream>>>(srcv, dstv, cursor, col, NE);

    // layer 1
    gemm_x_w1<<<(NN + 7) / 8, 256, 0, stream>>>(x, W1, deg_inv, h1s, NN);
    conv32_kernel<<<((size_t)NN * 32 + 255) / 256, 256, 0, stream>>>(row_ptr, col, h1s, deg_inv, b1, out1);

    // layer 2
    gemm_h_w2<<<(NN + 3) / 4, 256, 0, stream>>>(out1, W2, deg_inv, h2s, NN);
    conv64_kernel<<<((size_t)NN * 64 + 255) / 256, 256, 0, stream>>>(row_ptr, col, h2s, deg_inv, b2, out2);

    // pooling + head
    pool_kernel<<<(((NN + 15) / 16) * 64 + 255) / 256, 256, 0, stream>>>(out2, batch, gsum, gcnt, NN);
    head_kernel<<<1, 256, 0, stream>>>(gsum, gcnt, fcW1, fcb1, gamma, beta, fcW2, fcb2, out);
}